// Round 20
// baseline (290.928 us; speedup 1.0000x reference)
//
#include <hip/hip_runtime.h>
#include <hip/hip_bf16.h>

typedef float f32x4 __attribute__((ext_vector_type(4)));
typedef short s16x8 __attribute__((ext_vector_type(8)));

#define MFMA16(A,B,C) __builtin_amdgcn_mfma_f32_16x16x32_bf16((A),(B),(C),0,0,0)

// Hardware RNE f32->bf16 (v_cvt_pk_bf16_f32 when paired).
__device__ __forceinline__ short f2bf(float f) {
  return (short)__bfloat16_as_ushort(__float2bfloat16(f));
}

__device__ __forceinline__ void gload_lds16(const void* g, void* l) {
  __builtin_amdgcn_global_load_lds(
      (const __attribute__((address_space(1))) unsigned*)g,
      (__attribute__((address_space(3))) unsigned*)l, 16, 0, 0);
}

// ---------------- prep: weights -> bf16[N][K], gather bias table --------------
__global__ __launch_bounds__(256) void prep_kernel(
    const float* __restrict__ Wqkv, const float* __restrict__ Wo,
    const float* __restrict__ posb, const int* __restrict__ relp,
    short* __restrict__ WqkvT, short* __restrict__ WoT, float* __restrict__ biasF)
{
  int i = blockIdx.x * 256 + threadIdx.x;     // 2496*256 = 638,976 exactly
  if (i < 1152 * 384) {
    int n = i / 384, k = i % 384;
    WqkvT[i] = f2bf(Wqkv[k * 1152 + n]);
  } else if (i < 1152 * 384 + 384 * 384) {
    int j = i - 1152 * 384;
    int n = j / 384, k = j % 384;
    WoT[j] = f2bf(Wo[k * 384 + n]);
  } else {
    int j = i - (1152 * 384 + 384 * 384);     // j < 12*64*64 = 49152
    int h = j >> 12, qk = j & 4095;
    biasF[j] = posb[h * 16129 + relp[qk]];
  }
}

// ---------------- fused X-convert + QKV GEMM + attention (2 heads / block) ----
// R19 structure with the A prefetch deepened to a 2-ITERATION cover via a
// third register set. R19's vmcnt(6)-after-STAGE_B gave A only one COMPUTE
// (~500cy) of cover vs ~900cy HBM latency -> MfmaUtil fell 31.7->21.9.
// Issue-order walk (A*:8, B*:6): prologue A0 A1 A2 B0 B1; vmcnt(28)->AWRITE
// A0; vmcnt(20)->AWRITE A1; ALOAD A3.
//   tops (wait B(T), forces older A): 14, 22, 22, 14, 6, 0
//   bottoms: I0: B2, AWRITE(A2: forced at top), ALOAD A4
//            I1: B3, vmcnt(20), AWRITE(A3), ALOAD A5
//            I2: B4, vmcnt(20), AWRITE(A4)
//            I3: B5, vmcnt(12), AWRITE(A5)
// Every A-load is in flight for 2 full iterations. WAR/RAW ordering = the
// R7/R15-proven pattern (AWRITE only after the barrier following that
// buffer's lgkm-drained reads).
__global__ __launch_bounds__(256) void qkv_attn(
    const float* __restrict__ X, const short* __restrict__ WqkvT,
    const float* __restrict__ biasF, short* __restrict__ AO)
{
  __shared__ short lds[40960];   // A: sel*8192 | B: 16384 + sel*12288 (shorts)
  const int bid = blockIdx.x;
  const int wg = (bid & 7) * 588 + (bid >> 3);   // XCD swizzle (4704 = 8*588)
  const int hg = wg % 6, mt = wg / 6;
  const int t = threadIdx.x;
  const int wv = t >> 6, l = t & 63, lr = l & 15, lg = l >> 4;
  const int wm = wv >> 1, wn = wv & 1;

  f32x4 acc[6][4];               // [fn: q0,q1,k0,k1,v0,v1][fm: token block]
#pragma unroll
  for (int fn = 0; fn < 6; ++fn)
#pragma unroll
    for (int fm = 0; fm < 4; ++fm) acc[fn][fm] = (f32x4)0.0f;

  const int cgs = (l & 7) ^ (l >> 3);
  const float* Axf = X + (size_t)(mt * 128 + wv * 32 + (l >> 3)) * 384 + cgs * 8;
  const int adst = (wv * 32 + (l >> 3)) * 64 + (l & 7) * 8;  // + i*512, shorts
  const short* BbT[6];
#pragma unroll
  for (int j = 0; j < 6; ++j) {
    const int n0 = wv * 48 + j * 8 + (l >> 3);
    const int hl = n0 / 96, rem = n0 % 96;
    const int p = rem >> 5, d = rem & 31;
    BbT[j] = WqkvT + (size_t)(p * 384 + hg * 64 + hl * 32 + d) * 384 + cgs * 8;
  }

  float4 a0[8], a1[8], a2[8];

#define ALOAD(SET, KS) do {                                                  \
  _Pragma("unroll")                                                          \
  for (int i_ = 0; i_ < 4; ++i_) {                                           \
    const float* p_ = Axf + i_ * 8 * 384 + (KS) * 64;                        \
    SET[2 * i_]     = *(const float4*)p_;                                    \
    SET[2 * i_ + 1] = *(const float4*)(p_ + 4);                              \
  } } while (0)

#define AWRITE(SET, SEL) do {                                                \
  _Pragma("unroll")                                                          \
  for (int i_ = 0; i_ < 4; ++i_) {                                           \
    s16x8 pk_;                                                               \
    pk_[0] = f2bf(SET[2*i_].x);   pk_[1] = f2bf(SET[2*i_].y);                \
    pk_[2] = f2bf(SET[2*i_].z);   pk_[3] = f2bf(SET[2*i_].w);                \
    pk_[4] = f2bf(SET[2*i_+1].x); pk_[5] = f2bf(SET[2*i_+1].y);              \
    pk_[6] = f2bf(SET[2*i_+1].z); pk_[7] = f2bf(SET[2*i_+1].w);              \
    *(s16x8*)(lds + (SEL) * 8192 + adst + i_ * 512) = pk_;                   \
  } } while (0)

#define STAGE_B(KS, SEL) do {                                                \
  _Pragma("unroll")                                                          \
  for (int j_ = 0; j_ < 6; ++j_)                                             \
    gload_lds16(BbT[j_] + (KS) * 64,                                         \
                lds + 16384 + (SEL) * 12288 + (wv * 6 + j_) * 512);          \
  } while (0)

#define COMPUTE(SEL) do {                                                    \
  const short* Acur_ = lds + (SEL) * 8192;                                   \
  const short* Bcur_ = lds + 16384 + (SEL) * 12288;                          \
  _Pragma("unroll")                                                          \
  for (int kk = 0; kk < 2; ++kk) {                                           \
    s16x8 af[4], bq[6];                                                      \
    _Pragma("unroll")                                                        \
    for (int f = 0; f < 4; ++f) {                                            \
      const int arow = wm * 64 + f * 16 + lr;                                \
      const int ac = (kk * 4 + lg) ^ (arow & 7);                             \
      af[f] = *(const s16x8*)(Acur_ + arow * 64 + ac * 8);                   \
    }                                                                        \
    _Pragma("unroll")                                                        \
    for (int fn = 0; fn < 6; ++fn) {                                         \
      const int brow = wn * 96 + fn * 16 + lr;                               \
      const int bc = (kk * 4 + lg) ^ (brow & 7);                             \
      bq[fn] = *(const s16x8*)(Bcur_ + brow * 64 + bc * 8);                  \
    }                                                                        \
    _Pragma("unroll")                                                        \
    for (int fn = 0; fn < 6; ++fn)                                           \
      _Pragma("unroll")                                                      \
      for (int fm = 0; fm < 4; ++fm)                                         \
        acc[fn][fm] = MFMA16(bq[fn], af[fm], acc[fn][fm]);   /* W·X^T */     \
  } } while (0)

#define VMC(N)  asm volatile("s_waitcnt vmcnt(" #N ")" ::: "memory")
#define LGK0    asm volatile("s_waitcnt lgkmcnt(0)" ::: "memory")
#define TOP(T, WN) do {                                                      \
  VMC(WN);                                                                   \
  __builtin_amdgcn_s_barrier();                                              \
  COMPUTE((T) & 1);                                                          \
  LGK0;                                      /* WAR drain of buf reads */    \
  __builtin_amdgcn_s_barrier();                                              \
  } while (0)

  // ---- prologue: A0,A1,A2 (24 vm) + B0,B1 (12 vm) ----
  ALOAD(a0, 0);
  ALOAD(a1, 1);
  ALOAD(a2, 2);
  STAGE_B(0, 0);
  STAGE_B(1, 1);
  VMC(28);  AWRITE(a0, 0);                  // A0 landed
  VMC(20);  AWRITE(a1, 1);                  // A1 landed
  ALOAD(a0, 3);                             // A3 in flight (2-iter cover)
  LGK0;                                     // our ds_writes complete

  TOP(0, 14);                               // waits B0 (forces A2 too)
  STAGE_B(2, 0);  AWRITE(a2, 0);  ALOAD(a1, 4);  LGK0;

  TOP(1, 22);                               // waits B1
  STAGE_B(3, 1);  VMC(20);  AWRITE(a0, 1);  ALOAD(a2, 5);  LGK0;

  TOP(2, 22);                               // waits B2
  STAGE_B(4, 0);  VMC(20);  AWRITE(a1, 0);  LGK0;

  TOP(3, 14);                               // waits B3
  STAGE_B(5, 1);  VMC(12);  AWRITE(a2, 1);  LGK0;

  TOP(4, 6);                                // waits B4
  TOP(5, 0);                                // waits B5
#undef TOP
#undef LGK0
#undef VMC
#undef COMPUTE
#undef STAGE_B
#undef AWRITE
#undef ALOAD

  // final TOP's lgkm(0)+barrier drained all GEMM LDS reads block-wide;
  // per-wave attn scratch below may overwrite the staging region.

  // ---- attention, one (window, head) per wave; Q/K stay in registers ----
  const int w = mt * 2 + wm, h = hg * 2 + wn;
  short* Vts = lds + wv * 4992;          // [32][76] V^T (stride 76: no 4-way)
  short* Os  = Vts + 2432;               // [64][40] epilogue staging

  // V scatter: Vts[d][tok], d = fv*16+lg*4+r, tok = fm*16+lr
#pragma unroll
  for (int fv = 0; fv < 2; ++fv)
#pragma unroll
    for (int fm = 0; fm < 4; ++fm)
#pragma unroll
      for (int r = 0; r < 4; ++r)
        Vts[(fv * 16 + lg * 4 + r) * 76 + fm * 16 + lr] =
            f2bf(acc[4 + fv][fm][r]);

  // pack K (A-op: lane=row kt) and Q (B-op: lane=col q) frags in-register;
  // slot j -> d = 16*(j>>2) + 4*lg + (j&3)  (same sigma on both operands)
  s16x8 ka[4], qb[4];
#pragma unroll
  for (int f = 0; f < 4; ++f) {
    s16x8 tk, tq;
#pragma unroll
    for (int j = 0; j < 8; ++j) {
      tk[j] = f2bf(acc[2 + (j >> 2)][f][j & 3]);
      tq[j] = f2bf(acc[0 + (j >> 2)][f][j & 3]);
    }
    ka[f] = tk; qb[f] = tq;
  }

  // S^T = K·Q^T  (rows kt, cols q), K-dim 32
  f32x4 st[4][4];
#pragma unroll
  for (int fk = 0; fk < 4; ++fk)
#pragma unroll
    for (int fq = 0; fq < 4; ++fq)
      st[fk][fq] = MFMA16(ka[fk], qb[fq], (f32x4)0.0f);

  // scale + bias + softmax over kt (per q column, per-lane + shfl 16/32)
  const float* bh = biasF + h * 4096;
#pragma unroll
  for (int fq = 0; fq < 4; ++fq) {
    const int q = fq * 16 + lr;
    float4 bv[4];
#pragma unroll
    for (int fk = 0; fk < 4; ++fk)
      bv[fk] = *(const float4*)(bh + q * 64 + fk * 16 + lg * 4);
    float mx = -3.0e38f;
#pragma unroll
    for (int fk = 0; fk < 4; ++fk)
#pragma unroll
      for (int r = 0; r < 4; ++r) {
        float v = st[fk][fq][r] * 0.17677669529663687f + ((const float*)&bv[fk])[r];
        st[fk][fq][r] = v;
        mx = fmaxf(mx, v);
      }
    mx = fmaxf(mx, __shfl_xor(mx, 16));
    mx = fmaxf(mx, __shfl_xor(mx, 32));
    float sm = 0.0f;
#pragma unroll
    for (int fk = 0; fk < 4; ++fk)
#pragma unroll
      for (int r = 0; r < 4; ++r) {
        float e = __expf(st[fk][fq][r] - mx);
        st[fk][fq][r] = e;
        sm += e;
      }
    sm += __shfl_xor(sm, 16);
    sm += __shfl_xor(sm, 32);
    const float inv = 1.0f / sm;
#pragma unroll
    for (int fk = 0; fk < 4; ++fk)
#pragma unroll
      for (int r = 0; r < 4; ++r) st[fk][fq][r] *= inv;
  }

  // O^T = V^T · P^T ; sigma(g,j)=32kb+16(j>>2)+4g+(j&3) on both operands
  s16x8 va[2][2];
#pragma unroll
  for (int fd = 0; fd < 2; ++fd)
#pragma unroll
    for (int kb = 0; kb < 2; ++kb) {
      short4 v0 = *(const short4*)(Vts + (fd * 16 + lr) * 76 + kb * 32 + lg * 4);
      short4 v1 = *(const short4*)(Vts + (fd * 16 + lr) * 76 + kb * 32 + 16 + lg * 4);
      s16x8 tv;
      tv[0] = v0.x; tv[1] = v0.y; tv[2] = v0.z; tv[3] = v0.w;
      tv[4] = v1.x; tv[5] = v1.y; tv[6] = v1.z; tv[7] = v1.w;
      va[fd][kb] = tv;
    }
  f32x4 ot[2][4];
#pragma unroll
  for (int fd = 0; fd < 2; ++fd)
#pragma unroll
    for (int fq = 0; fq < 4; ++fq) ot[fd][fq] = (f32x4)0.0f;
#pragma unroll
  for (int kb = 0; kb < 2; ++kb)
#pragma unroll
    for (int fq = 0; fq < 4; ++fq) {
      s16x8 pb;
#pragma unroll
      for (int j = 0; j < 8; ++j)
        pb[j] = f2bf(st[2 * kb + (j >> 2)][fq][j & 3]);   // lane-local repack
#pragma unroll
      for (int fd = 0; fd < 2; ++fd)
        ot[fd][fq] = MFMA16(va[fd][kb], pb, ot[fd][fq]);
    }

  // epilogue: stage O [q][d] in Os, write coalesced 64B rows
#pragma unroll
  for (int fd = 0; fd < 2; ++fd)
#pragma unroll
    for (int fq = 0; fq < 4; ++fq)
#pragma unroll
      for (int r = 0; r < 4; ++r)
        Os[(fq * 16 + lr) * 40 + fd * 16 + lg * 4 + r] = f2bf(ot[fd][fq][r]);
  short* dst = AO + ((size_t)w * 64 + l) * 384 + h * 32;
  int4 o0 = *(const int4*)(Os + l * 40);
  int4 o1 = *(const int4*)(Os + l * 40 + 8);
  int4 o2 = *(const int4*)(Os + l * 40 + 16);
  int4 o3 = *(const int4*)(Os + l * 40 + 24);
  *(int4*)(dst)      = o0;
  *(int4*)(dst + 8)  = o1;
  *(int4*)(dst + 16) = o2;
  *(int4*)(dst + 24) = o3;
}

// ---------------- output projection: out = AO(bf16) @ Wo + bo, f32 out --------
// R7-proven BK=64 2-deep counted-vmcnt pipeline.
__global__ __launch_bounds__(256) void proj_kernel(
    const short* __restrict__ AO, const short* __restrict__ WoT,
    const float* __restrict__ bo, float* __restrict__ out)
{
  __shared__ short lds[32768];
  const int bid = blockIdx.x;
  const int wg = (bid & 7) * 294 + (bid >> 3);   // XCD swizzle (2352 = 8*294)
  const int nt = wg % 3, mt = wg / 3;
  const int t = threadIdx.x;
  const int wv = t >> 6, l = t & 63, lr = l & 15, lg = l >> 4;
  const int wm = wv >> 1, wn = wv & 1;

  f32x4 acc[4][4];
#pragma unroll
  for (int fm = 0; fm < 4; ++fm)
#pragma unroll
    for (int fn = 0; fn < 4; ++fn) acc[fm][fn] = (f32x4)0.0f;

  const int srow = wv * 32 + (l >> 3);
  const int cg = (l & 7) ^ (srow & 7);
  const short* Ab = AO  + (size_t)(mt * 128 + srow) * 384 + cg * 8;
  const short* Bb = WoT + (size_t)(nt * 128 + srow) * 384 + cg * 8;

#define STAGE(KS, SEL) do {                                                  \
  _Pragma("unroll")                                                          \
  for (int i_ = 0; i_ < 4; ++i_) {                                           \
    gload_lds16(Ab + i_ * 3072 + (KS) * 64,                                  \
                lds + (SEL) * 16384 + (wv * 4 + i_) * 512);                  \
    gload_lds16(Bb + i_ * 3072 + (KS) * 64,                                  \
                lds + (SEL) * 16384 + 8192 + (wv * 4 + i_) * 512);           \
  } } while (0)

#define COMPUTE(SEL) do {                                                    \
  const short* Acur_ = lds + (SEL) * 16384;                                  \
  const short* Bcur_ = Acur_ + 8192;                                         \
  _Pragma("unroll")                                                          \
  for (int kk = 0; kk < 2; ++kk) {                                           \
    s16x8 af[4], bf[4];                                                      \
    _Pragma("unroll")                                                        \
    for (int f = 0; f < 4; ++f) {                                            \
      const int arow = wm * 64 + f * 16 + lr;                                \
      const int ac = (kk * 4 + lg) ^ (arow & 7);                             \
      af[f] = *(const s16x8*)(Acur_ + arow * 64 + ac * 8);                   \
      const int brow = wn * 64 + f * 16 + lr;                                \
      const int bc = (kk * 4 + lg) ^ (brow & 7);                             \
      bf[f] = *(const s16x8*)(Bcur_ + brow * 64 + bc * 8);                   \
    }                                                                        \
    _Pragma("unroll")                                                        \
    for (int fm = 0; fm < 4; ++fm)                                           \
      _Pragma("unroll")                                                      \
      for (int fn = 0; fn < 4; ++fn)                                         \
        acc[fm][fn] = MFMA16(af[fm], bf[fn], acc[fm][fn]);                   \
  } } while (0)

#define ITER(T, WN) do {                                                     \
  asm volatile("s_waitcnt vmcnt(" #WN ")" ::: "memory");                     \
  __builtin_amdgcn_s_barrier();                                              \
  COMPUTE((T) & 1);                                                          \
  asm volatile("s_waitcnt lgkmcnt(0)" ::: "memory");  /* WAR drain */        \
  __builtin_amdgcn_s_barrier();                                              \
  if ((T) + 2 < 6) STAGE((T) + 2, (T) & 1);                                  \
  } while (0)

  STAGE(0, 0);
  STAGE(1, 1);
  ITER(0, 8); ITER(1, 8); ITER(2, 8); ITER(3, 8); ITER(4, 8); ITER(5, 0);
#undef ITER
#undef COMPUTE
#undef STAGE

#pragma unroll
  for (int fn = 0; fn < 4; ++fn) {
    const int n = nt * 128 + wn * 64 + fn * 16 + lr;
    const float bias = bo[n];
#pragma unroll
    for (int fm = 0; fm < 4; ++fm) {
      const int m0 = mt * 128 + wm * 64 + fm * 16 + lg * 4;
#pragma unroll
      for (int r = 0; r < 4; ++r)
        out[(size_t)(m0 + r) * 384 + n] = acc[fm][fn][r] + bias;
    }
  }
}

extern "C" void kernel_launch(void* const* d_in, const int* in_sizes, int n_in,
                              void* d_out, int out_size, void* d_ws, size_t ws_size,
                              hipStream_t stream)
{
  const float* X    = (const float*)d_in[0];
  const float* Wqkv = (const float*)d_in[1];
  const float* posb = (const float*)d_in[2];
  const float* Wo   = (const float*)d_in[3];
  const float* bo   = (const float*)d_in[4];
  const int*   relp = (const int*)d_in[5];
  float* out = (float*)d_out;

  // workspace carve — ~78.5 MB (Xbf eliminated)
  char* ws = (char*)d_ws;
  short* WqkvT = (short*)(ws);                 //   884,736 B
  short* WoT   = (short*)(ws + 884736);        //   294,912 B
  float* biasF = (float*)(ws + 1179648);       //   196,608 B
  short* AO    = (short*)(ws + 1376256);       // 77,070,336 B [100352][384]

  prep_kernel<<<2496, 256, 0, stream>>>(Wqkv, Wo, posb, relp, WqkvT, WoT, biasF);
  qkv_attn<<<4704, 256, 0, stream>>>(X, WqkvT, biasF, AO);
  proj_kernel<<<2352, 256, 0, stream>>>(AO, WoT, bo, out);
}

// Round 21
// 224.257 us; speedup vs baseline: 1.2973x; 1.2973x over previous
//
#include <hip/hip_runtime.h>
#include <hip/hip_bf16.h>

typedef float f32x4 __attribute__((ext_vector_type(4)));
typedef short s16x8 __attribute__((ext_vector_type(8)));

#define MFMA16(A,B,C) __builtin_amdgcn_mfma_f32_16x16x32_bf16((A),(B),(C),0,0,0)

// Hardware RNE f32->bf16 (v_cvt_pk_bf16_f32 when paired).
__device__ __forceinline__ short f2bf(float f) {
  return (short)__bfloat16_as_ushort(__float2bfloat16(f));
}

__device__ __forceinline__ void gload_lds16(const void* g, void* l) {
  __builtin_amdgcn_global_load_lds(
      (const __attribute__((address_space(1))) unsigned*)g,
      (__attribute__((address_space(3))) unsigned*)l, 16, 0, 0);
}

// ---------------- prep: weights -> bf16[N][K], gather bias table --------------
__global__ __launch_bounds__(256) void prep_kernel(
    const float* __restrict__ Wqkv, const float* __restrict__ Wo,
    const float* __restrict__ posb, const int* __restrict__ relp,
    short* __restrict__ WqkvT, short* __restrict__ WoT, float* __restrict__ biasF)
{
  int i = blockIdx.x * 256 + threadIdx.x;     // 2496*256 = 638,976 exactly
  if (i < 1152 * 384) {
    int n = i / 384, k = i % 384;
    WqkvT[i] = f2bf(Wqkv[k * 1152 + n]);
  } else if (i < 1152 * 384 + 384 * 384) {
    int j = i - 1152 * 384;
    int n = j / 384, k = j % 384;
    WoT[j] = f2bf(Wo[k * 384 + n]);
  } else {
    int j = i - (1152 * 384 + 384 * 384);     // j < 12*64*64 = 49152
    int h = j >> 12, qk = j & 4095;
    biasF[j] = posb[h * 16129 + relp[qk]];
  }
}

// ---------------- fused X-convert + QKV GEMM + attention (2 heads / block) ----
// R19 structure; A prefetch deepened to ~2-COMPUTE cover with NO extra
// register set (R20's third set pushed VGPR 124->140, occupancy 21->11%,
// catastrophic). Trick: ALOAD at the TOP of the iteration (the set not
// pending a write is free there). Issue order:
//   A0 A1 B0 B1 A2 | A3 B2 | A4 B3 | A5 B4 | B5
// prologue: vmcnt(20) AWRITE(a0); vmcnt(12) AWRITE(a1); ALOAD(a0,2); lgkm0
// tops (wait B(T)):    14,14,14,14,6,0 ; ALOAD(T+3) after barrier for T<=2
// bottoms (wait A(T+2) before AWRITE): 14,20,20,12
// WAR ordering = R7/R15-proven (AWRITE only after the barrier following the
// lgkm-drained reads of that buffer).
__global__ __launch_bounds__(256) void qkv_attn(
    const float* __restrict__ X, const short* __restrict__ WqkvT,
    const float* __restrict__ biasF, short* __restrict__ AO)
{
  __shared__ short lds[40960];   // A: sel*8192 | B: 16384 + sel*12288 (shorts)
  const int bid = blockIdx.x;
  const int wg = (bid & 7) * 588 + (bid >> 3);   // XCD swizzle (4704 = 8*588)
  const int hg = wg % 6, mt = wg / 6;
  const int t = threadIdx.x;
  const int wv = t >> 6, l = t & 63, lr = l & 15, lg = l >> 4;
  const int wm = wv >> 1, wn = wv & 1;

  f32x4 acc[6][4];               // [fn: q0,q1,k0,k1,v0,v1][fm: token block]
#pragma unroll
  for (int fn = 0; fn < 6; ++fn)
#pragma unroll
    for (int fm = 0; fm < 4; ++fm) acc[fn][fm] = (f32x4)0.0f;

  const int cgs = (l & 7) ^ (l >> 3);
  const float* Axf = X + (size_t)(mt * 128 + wv * 32 + (l >> 3)) * 384 + cgs * 8;
  const int adst = (wv * 32 + (l >> 3)) * 64 + (l & 7) * 8;  // + i*512, shorts
  const short* BbT[6];
#pragma unroll
  for (int j = 0; j < 6; ++j) {
    const int n0 = wv * 48 + j * 8 + (l >> 3);
    const int hl = n0 / 96, rem = n0 % 96;
    const int p = rem >> 5, d = rem & 31;
    BbT[j] = WqkvT + (size_t)(p * 384 + hg * 64 + hl * 32 + d) * 384 + cgs * 8;
  }

  float4 a0[8], a1[8];

#define ALOAD(SET, KS) do {                                                  \
  _Pragma("unroll")                                                          \
  for (int i_ = 0; i_ < 4; ++i_) {                                           \
    const float* p_ = Axf + i_ * 8 * 384 + (KS) * 64;                        \
    SET[2 * i_]     = *(const float4*)p_;                                    \
    SET[2 * i_ + 1] = *(const float4*)(p_ + 4);                              \
  } } while (0)

#define AWRITE(SET, SEL) do {                                                \
  _Pragma("unroll")                                                          \
  for (int i_ = 0; i_ < 4; ++i_) {                                           \
    s16x8 pk_;                                                               \
    pk_[0] = f2bf(SET[2*i_].x);   pk_[1] = f2bf(SET[2*i_].y);                \
    pk_[2] = f2bf(SET[2*i_].z);   pk_[3] = f2bf(SET[2*i_].w);                \
    pk_[4] = f2bf(SET[2*i_+1].x); pk_[5] = f2bf(SET[2*i_+1].y);              \
    pk_[6] = f2bf(SET[2*i_+1].z); pk_[7] = f2bf(SET[2*i_+1].w);              \
    *(s16x8*)(lds + (SEL) * 8192 + adst + i_ * 512) = pk_;                   \
  } } while (0)

#define STAGE_B(KS, SEL) do {                                                \
  _Pragma("unroll")                                                          \
  for (int j_ = 0; j_ < 6; ++j_)                                             \
    gload_lds16(BbT[j_] + (KS) * 64,                                         \
                lds + 16384 + (SEL) * 12288 + (wv * 6 + j_) * 512);          \
  } while (0)

#define COMPUTE(SEL) do {                                                    \
  const short* Acur_ = lds + (SEL) * 8192;                                   \
  const short* Bcur_ = lds + 16384 + (SEL) * 12288;                          \
  _Pragma("unroll")                                                          \
  for (int kk = 0; kk < 2; ++kk) {                                           \
    s16x8 af[4], bq[6];                                                      \
    _Pragma("unroll")                                                        \
    for (int f = 0; f < 4; ++f) {                                            \
      const int arow = wm * 64 + f * 16 + lr;                                \
      const int ac = (kk * 4 + lg) ^ (arow & 7);                             \
      af[f] = *(const s16x8*)(Acur_ + arow * 64 + ac * 8);                   \
    }                                                                        \
    _Pragma("unroll")                                                        \
    for (int fn = 0; fn < 6; ++fn) {                                         \
      const int brow = wn * 96 + fn * 16 + lr;                               \
      const int bc = (kk * 4 + lg) ^ (brow & 7);                             \
      bq[fn] = *(const s16x8*)(Bcur_ + brow * 64 + bc * 8);                  \
    }                                                                        \
    _Pragma("unroll")                                                        \
    for (int fn = 0; fn < 6; ++fn)                                           \
      _Pragma("unroll")                                                      \
      for (int fm = 0; fm < 4; ++fm)                                         \
        acc[fn][fm] = MFMA16(bq[fn], af[fm], acc[fn][fm]);   /* W·X^T */     \
  } } while (0)

#define VMC(N)  asm volatile("s_waitcnt vmcnt(" #N ")" ::: "memory")
#define LGK0    asm volatile("s_waitcnt lgkmcnt(0)" ::: "memory")

  // ---- prologue: A0,A1 (16 vm) + B0,B1 (12 vm) ----
  ALOAD(a0, 0);
  ALOAD(a1, 1);
  STAGE_B(0, 0);
  STAGE_B(1, 1);
  VMC(20);  AWRITE(a0, 0);                  // A0 landed
  VMC(12);  AWRITE(a1, 1);                  // A1 landed
  ALOAD(a0, 2);                             // A2 in flight
  LGK0;                                     // our ds_writes complete

  // ---- ITER 0 ----
  VMC(14);  __builtin_amdgcn_s_barrier();   // B0 ready
  ALOAD(a1, 3);                             // A3, ~2-COMPUTE cover
  COMPUTE(0);
  LGK0;     __builtin_amdgcn_s_barrier();   // buf0 reads drained
  STAGE_B(2, 0);
  VMC(14);  AWRITE(a0, 0);  LGK0;           // A2 -> buf0

  // ---- ITER 1 ----
  VMC(14);  __builtin_amdgcn_s_barrier();   // B1 ready (older than A2)
  ALOAD(a0, 4);                             // A4
  COMPUTE(1);
  LGK0;     __builtin_amdgcn_s_barrier();
  STAGE_B(3, 1);
  VMC(20);  AWRITE(a1, 1);  LGK0;           // A3 -> buf1

  // ---- ITER 2 ----
  VMC(14);  __builtin_amdgcn_s_barrier();   // B2 ready
  ALOAD(a1, 5);                             // A5
  COMPUTE(0);
  LGK0;     __builtin_amdgcn_s_barrier();
  STAGE_B(4, 0);
  VMC(20);  AWRITE(a0, 0);  LGK0;           // A4 -> buf0

  // ---- ITER 3 ----
  VMC(14);  __builtin_amdgcn_s_barrier();   // B3 ready
  COMPUTE(1);
  LGK0;     __builtin_amdgcn_s_barrier();
  STAGE_B(5, 1);
  VMC(12);  AWRITE(a1, 1);  LGK0;           // A5 -> buf1

  // ---- ITER 4 ----
  VMC(6);   __builtin_amdgcn_s_barrier();   // B4 ready
  COMPUTE(0);
  LGK0;     __builtin_amdgcn_s_barrier();

  // ---- ITER 5 ----
  VMC(0);   __builtin_amdgcn_s_barrier();   // B5 ready
  COMPUTE(1);
  LGK0;     __builtin_amdgcn_s_barrier();

#undef LGK0
#undef VMC
#undef COMPUTE
#undef STAGE_B
#undef AWRITE
#undef ALOAD

  // ---- attention, one (window, head) per wave; Q/K stay in registers ----
  const int w = mt * 2 + wm, h = hg * 2 + wn;
  short* Vts = lds + wv * 4992;          // [32][76] V^T (stride 76: no 4-way)
  short* Os  = Vts + 2432;               // [64][40] epilogue staging

  // V scatter: Vts[d][tok], d = fv*16+lg*4+r, tok = fm*16+lr
#pragma unroll
  for (int fv = 0; fv < 2; ++fv)
#pragma unroll
    for (int fm = 0; fm < 4; ++fm)
#pragma unroll
      for (int r = 0; r < 4; ++r)
        Vts[(fv * 16 + lg * 4 + r) * 76 + fm * 16 + lr] =
            f2bf(acc[4 + fv][fm][r]);

  // pack K (A-op: lane=row kt) and Q (B-op: lane=col q) frags in-register;
  // slot j -> d = 16*(j>>2) + 4*lg + (j&3)  (same sigma on both operands)
  s16x8 ka[4], qb[4];
#pragma unroll
  for (int f = 0; f < 4; ++f) {
    s16x8 tk, tq;
#pragma unroll
    for (int j = 0; j < 8; ++j) {
      tk[j] = f2bf(acc[2 + (j >> 2)][f][j & 3]);
      tq[j] = f2bf(acc[0 + (j >> 2)][f][j & 3]);
    }
    ka[f] = tk; qb[f] = tq;
  }

  // S^T = K·Q^T  (rows kt, cols q), K-dim 32
  f32x4 st[4][4];
#pragma unroll
  for (int fk = 0; fk < 4; ++fk)
#pragma unroll
    for (int fq = 0; fq < 4; ++fq)
      st[fk][fq] = MFMA16(ka[fk], qb[fq], (f32x4)0.0f);

  // scale + bias + softmax over kt (per q column, per-lane + shfl 16/32)
  const float* bh = biasF + h * 4096;
#pragma unroll
  for (int fq = 0; fq < 4; ++fq) {
    const int q = fq * 16 + lr;
    float4 bv[4];
#pragma unroll
    for (int fk = 0; fk < 4; ++fk)
      bv[fk] = *(const float4*)(bh + q * 64 + fk * 16 + lg * 4);
    float mx = -3.0e38f;
#pragma unroll
    for (int fk = 0; fk < 4; ++fk)
#pragma unroll
      for (int r = 0; r < 4; ++r) {
        float v = st[fk][fq][r] * 0.17677669529663687f + ((const float*)&bv[fk])[r];
        st[fk][fq][r] = v;
        mx = fmaxf(mx, v);
      }
    mx = fmaxf(mx, __shfl_xor(mx, 16));
    mx = fmaxf(mx, __shfl_xor(mx, 32));
    float sm = 0.0f;
#pragma unroll
    for (int fk = 0; fk < 4; ++fk)
#pragma unroll
      for (int r = 0; r < 4; ++r) {
        float e = __expf(st[fk][fq][r] - mx);
        st[fk][fq][r] = e;
        sm += e;
      }
    sm += __shfl_xor(sm, 16);
    sm += __shfl_xor(sm, 32);
    const float inv = 1.0f / sm;
#pragma unroll
    for (int fk = 0; fk < 4; ++fk)
#pragma unroll
      for (int r = 0; r < 4; ++r) st[fk][fq][r] *= inv;
  }

  // O^T = V^T · P^T ; sigma(g,j)=32kb+16(j>>2)+4g+(j&3) on both operands
  s16x8 va[2][2];
#pragma unroll
  for (int fd = 0; fd < 2; ++fd)
#pragma unroll
    for (int kb = 0; kb < 2; ++kb) {
      short4 v0 = *(const short4*)(Vts + (fd * 16 + lr) * 76 + kb * 32 + lg * 4);
      short4 v1 = *(const short4*)(Vts + (fd * 16 + lr) * 76 + kb * 32 + 16 + lg * 4);
      s16x8 tv;
      tv[0] = v0.x; tv[1] = v0.y; tv[2] = v0.z; tv[3] = v0.w;
      tv[4] = v1.x; tv[5] = v1.y; tv[6] = v1.z; tv[7] = v1.w;
      va[fd][kb] = tv;
    }
  f32x4 ot[2][4];
#pragma unroll
  for (int fd = 0; fd < 2; ++fd)
#pragma unroll
    for (int fq = 0; fq < 4; ++fq) ot[fd][fq] = (f32x4)0.0f;
#pragma unroll
  for (int kb = 0; kb < 2; ++kb)
#pragma unroll
    for (int fq = 0; fq < 4; ++fq) {
      s16x8 pb;
#pragma unroll
      for (int j = 0; j < 8; ++j)
        pb[j] = f2bf(st[2 * kb + (j >> 2)][fq][j & 3]);   // lane-local repack
#pragma unroll
      for (int fd = 0; fd < 2; ++fd)
        ot[fd][fq] = MFMA16(va[fd][kb], pb, ot[fd][fq]);
    }

  // epilogue: stage O [q][d] in Os, write coalesced 64B rows
#pragma unroll
  for (int fd = 0; fd < 2; ++fd)
#pragma unroll
    for (int fq = 0; fq < 4; ++fq)
#pragma unroll
      for (int r = 0; r < 4; ++r)
        Os[(fq * 16 + lr) * 40 + fd * 16 + lg * 4 + r] = f2bf(ot[fd][fq][r]);
  short* dst = AO + ((size_t)w * 64 + l) * 384 + h * 32;
  int4 o0 = *(const int4*)(Os + l * 40);
  int4 o1 = *(const int4*)(Os + l * 40 + 8);
  int4 o2 = *(const int4*)(Os + l * 40 + 16);
  int4 o3 = *(const int4*)(Os + l * 40 + 24);
  *(int4*)(dst)      = o0;
  *(int4*)(dst + 8)  = o1;
  *(int4*)(dst + 16) = o2;
  *(int4*)(dst + 24) = o3;
}

// ---------------- output projection: out = AO(bf16) @ Wo + bo, f32 out --------
// R7-proven BK=64 2-deep counted-vmcnt pipeline.
__global__ __launch_bounds__(256) void proj_kernel(
    const short* __restrict__ AO, const short* __restrict__ WoT,
    const float* __restrict__ bo, float* __restrict__ out)
{
  __shared__ short lds[32768];
  const int bid = blockIdx.x;
  const int wg = (bid & 7) * 294 + (bid >> 3);   // XCD swizzle (2352 = 8*294)
  const int nt = wg % 3, mt = wg / 3;
  const int t = threadIdx.x;
  const int wv = t >> 6, l = t & 63, lr = l & 15, lg = l >> 4;
  const int wm = wv >> 1, wn = wv & 1;

  f32x4 acc[4][4];
#pragma unroll
  for (int fm = 0; fm < 4; ++fm)
#pragma unroll
    for (int fn = 0; fn < 4; ++fn) acc[fm][fn] = (f32x4)0.0f;

  const int srow = wv * 32 + (l >> 3);
  const int cg = (l & 7) ^ (srow & 7);
  const short* Ab = AO  + (size_t)(mt * 128 + srow) * 384 + cg * 8;
  const short* Bb = WoT + (size_t)(nt * 128 + srow) * 384 + cg * 8;

#define STAGE(KS, SEL) do {                                                  \
  _Pragma("unroll")                                                          \
  for (int i_ = 0; i_ < 4; ++i_) {                                           \
    gload_lds16(Ab + i_ * 3072 + (KS) * 64,                                  \
                lds + (SEL) * 16384 + (wv * 4 + i_) * 512);                  \
    gload_lds16(Bb + i_ * 3072 + (KS) * 64,                                  \
                lds + (SEL) * 16384 + 8192 + (wv * 4 + i_) * 512);           \
  } } while (0)

#define COMPUTE(SEL) do {                                                    \
  const short* Acur_ = lds + (SEL) * 16384;                                  \
  const short* Bcur_ = Acur_ + 8192;                                         \
  _Pragma("unroll")                                                          \
  for (int kk = 0; kk < 2; ++kk) {                                           \
    s16x8 af[4], bf[4];                                                      \
    _Pragma("unroll")                                                        \
    for (int f = 0; f < 4; ++f) {                                            \
      const int arow = wm * 64 + f * 16 + lr;                                \
      const int ac = (kk * 4 + lg) ^ (arow & 7);                             \
      af[f] = *(const s16x8*)(Acur_ + arow * 64 + ac * 8);                   \
      const int brow = wn * 64 + f * 16 + lr;                                \
      const int bc = (kk * 4 + lg) ^ (brow & 7);                             \
      bf[f] = *(const s16x8*)(Bcur_ + brow * 64 + bc * 8);                   \
    }                                                                        \
    _Pragma("unroll")                                                        \
    for (int fm = 0; fm < 4; ++fm)                                           \
      _Pragma("unroll")                                                      \
      for (int fn = 0; fn < 4; ++fn)                                         \
        acc[fm][fn] = MFMA16(af[fm], bf[fn], acc[fm][fn]);                   \
  } } while (0)

#define ITER(T, WN) do {                                                     \
  asm volatile("s_waitcnt vmcnt(" #WN ")" ::: "memory");                     \
  __builtin_amdgcn_s_barrier();                                              \
  COMPUTE((T) & 1);                                                          \
  asm volatile("s_waitcnt lgkmcnt(0)" ::: "memory");  /* WAR drain */        \
  __builtin_amdgcn_s_barrier();                                              \
  if ((T) + 2 < 6) STAGE((T) + 2, (T) & 1);                                  \
  } while (0)

  STAGE(0, 0);
  STAGE(1, 1);
  ITER(0, 8); ITER(1, 8); ITER(2, 8); ITER(3, 8); ITER(4, 8); ITER(5, 0);
#undef ITER
#undef COMPUTE
#undef STAGE

#pragma unroll
  for (int fn = 0; fn < 4; ++fn) {
    const int n = nt * 128 + wn * 64 + fn * 16 + lr;
    const float bias = bo[n];
#pragma unroll
    for (int fm = 0; fm < 4; ++fm) {
      const int m0 = mt * 128 + wm * 64 + fm * 16 + lg * 4;
#pragma unroll
      for (int r = 0; r < 4; ++r)
        out[(size_t)(m0 + r) * 384 + n] = acc[fm][fn][r] + bias;
    }
  }
}

extern "C" void kernel_launch(void* const* d_in, const int* in_sizes, int n_in,
                              void* d_out, int out_size, void* d_ws, size_t ws_size,
                              hipStream_t stream)
{
  const float* X    = (const float*)d_in[0];
  const float* Wqkv = (const float*)d_in[1];
  const float* posb = (const float*)d_in[2];
  const float* Wo   = (const float*)d_in[3];
  const float* bo   = (const float*)d_in[4];
  const int*   relp = (const int*)d_in[5];
  float* out = (float*)d_out;

  // workspace carve — ~78.5 MB (Xbf eliminated)
  char* ws = (char*)d_ws;
  short* WqkvT = (short*)(ws);                 //   884,736 B
  short* WoT   = (short*)(ws + 884736);        //   294,912 B
  float* biasF = (float*)(ws + 1179648);       //   196,608 B
  short* AO    = (short*)(ws + 1376256);       // 77,070,336 B [100352][384]

  prep_kernel<<<2496, 256, 0, stream>>>(Wqkv, Wo, posb, relp, WqkvT, WoT, biasF);
  qkv_attn<<<4704, 256, 0, stream>>>(X, WqkvT, biasF, AO);
  proj_kernel<<<2352, 256, 0, stream>>>(AO, WoT, bo, out);
}

// Round 22
// 221.877 us; speedup vs baseline: 1.3112x; 1.0107x over previous
//
#include <hip/hip_runtime.h>
#include <hip/hip_bf16.h>

typedef float f32x4 __attribute__((ext_vector_type(4)));
typedef short s16x8 __attribute__((ext_vector_type(8)));

#define MFMA16(A,B,C) __builtin_amdgcn_mfma_f32_16x16x32_bf16((A),(B),(C),0,0,0)

// Hardware RNE f32->bf16 (v_cvt_pk_bf16_f32 when paired).
__device__ __forceinline__ short f2bf(float f) {
  return (short)__bfloat16_as_ushort(__float2bfloat16(f));
}

__device__ __forceinline__ void gload_lds16(const void* g, void* l) {
  __builtin_amdgcn_global_load_lds(
      (const __attribute__((address_space(1))) unsigned*)g,
      (__attribute__((address_space(3))) unsigned*)l, 16, 0, 0);
}

// ---------------- prep: weights -> bf16[N][K], gather bias table --------------
__global__ __launch_bounds__(256) void prep_kernel(
    const float* __restrict__ Wqkv, const float* __restrict__ Wo,
    const float* __restrict__ posb, const int* __restrict__ relp,
    short* __restrict__ WqkvT, short* __restrict__ WoT, float* __restrict__ biasF)
{
  int i = blockIdx.x * 256 + threadIdx.x;     // 2496*256 = 638,976 exactly
  if (i < 1152 * 384) {
    int n = i / 384, k = i % 384;
    WqkvT[i] = f2bf(Wqkv[k * 1152 + n]);
  } else if (i < 1152 * 384 + 384 * 384) {
    int j = i - 1152 * 384;
    int n = j / 384, k = j % 384;
    WoT[j] = f2bf(Wo[k * 384 + n]);
  } else {
    int j = i - (1152 * 384 + 384 * 384);     // j < 12*64*64 = 49152
    int h = j >> 12, qk = j & 4095;
    biasF[j] = posb[h * 16129 + relp[qk]];
  }
}

// ---------------- fused X-convert + QKV GEMM + attention (2 heads / block) ----
// R19 schedule restored EXACTLY (best: 221.2us total, qkv 194us), plus T5
// s_setprio(1/0) around the MFMA cluster (structure-conditional: helps when
// co-resident blocks are at different phases — our 2 blocks/CU + attn tail).
// R20 (3rd reg set: VGPR 140, occ 11%) and R21 (top-ALOAD) both refuted.
__global__ __launch_bounds__(256) void qkv_attn(
    const float* __restrict__ X, const short* __restrict__ WqkvT,
    const float* __restrict__ biasF, short* __restrict__ AO)
{
  __shared__ short lds[40960];   // A: sel*8192 | B: 16384 + sel*12288 (shorts)
  const int bid = blockIdx.x;
  const int wg = (bid & 7) * 588 + (bid >> 3);   // XCD swizzle (4704 = 8*588)
  const int hg = wg % 6, mt = wg / 6;
  const int t = threadIdx.x;
  const int wv = t >> 6, l = t & 63, lr = l & 15, lg = l >> 4;
  const int wm = wv >> 1, wn = wv & 1;

  f32x4 acc[6][4];               // [fn: q0,q1,k0,k1,v0,v1][fm: token block]
#pragma unroll
  for (int fn = 0; fn < 6; ++fn)
#pragma unroll
    for (int fm = 0; fm < 4; ++fm) acc[fn][fm] = (f32x4)0.0f;

  const int cgs = (l & 7) ^ (l >> 3);
  const float* Axf = X + (size_t)(mt * 128 + wv * 32 + (l >> 3)) * 384 + cgs * 8;
  const int adst = (wv * 32 + (l >> 3)) * 64 + (l & 7) * 8;  // + i*512, shorts
  const short* BbT[6];
#pragma unroll
  for (int j = 0; j < 6; ++j) {
    const int n0 = wv * 48 + j * 8 + (l >> 3);
    const int hl = n0 / 96, rem = n0 % 96;
    const int p = rem >> 5, d = rem & 31;
    BbT[j] = WqkvT + (size_t)(p * 384 + hg * 64 + hl * 32 + d) * 384 + cgs * 8;
  }

  float4 a0[8], a1[8];

#define ALOAD(SET, KS) do {                                                  \
  _Pragma("unroll")                                                          \
  for (int i_ = 0; i_ < 4; ++i_) {                                           \
    const float* p_ = Axf + i_ * 8 * 384 + (KS) * 64;                        \
    SET[2 * i_]     = *(const float4*)p_;                                    \
    SET[2 * i_ + 1] = *(const float4*)(p_ + 4);                              \
  } } while (0)

#define AWRITE(SET, SEL) do {                                                \
  _Pragma("unroll")                                                          \
  for (int i_ = 0; i_ < 4; ++i_) {                                           \
    s16x8 pk_;                                                               \
    pk_[0] = f2bf(SET[2*i_].x);   pk_[1] = f2bf(SET[2*i_].y);                \
    pk_[2] = f2bf(SET[2*i_].z);   pk_[3] = f2bf(SET[2*i_].w);                \
    pk_[4] = f2bf(SET[2*i_+1].x); pk_[5] = f2bf(SET[2*i_+1].y);              \
    pk_[6] = f2bf(SET[2*i_+1].z); pk_[7] = f2bf(SET[2*i_+1].w);              \
    *(s16x8*)(lds + (SEL) * 8192 + adst + i_ * 512) = pk_;                   \
  } } while (0)

#define STAGE_B(KS, SEL) do {                                                \
  _Pragma("unroll")                                                          \
  for (int j_ = 0; j_ < 6; ++j_)                                             \
    gload_lds16(BbT[j_] + (KS) * 64,                                         \
                lds + 16384 + (SEL) * 12288 + (wv * 6 + j_) * 512);          \
  } while (0)

#define COMPUTE(SEL) do {                                                    \
  const short* Acur_ = lds + (SEL) * 8192;                                   \
  const short* Bcur_ = lds + 16384 + (SEL) * 12288;                          \
  _Pragma("unroll")                                                          \
  for (int kk = 0; kk < 2; ++kk) {                                           \
    s16x8 af[4], bq[6];                                                      \
    _Pragma("unroll")                                                        \
    for (int f = 0; f < 4; ++f) {                                            \
      const int arow = wm * 64 + f * 16 + lr;                                \
      const int ac = (kk * 4 + lg) ^ (arow & 7);                             \
      af[f] = *(const s16x8*)(Acur_ + arow * 64 + ac * 8);                   \
    }                                                                        \
    _Pragma("unroll")                                                        \
    for (int fn = 0; fn < 6; ++fn) {                                         \
      const int brow = wn * 96 + fn * 16 + lr;                               \
      const int bc = (kk * 4 + lg) ^ (brow & 7);                             \
      bq[fn] = *(const s16x8*)(Bcur_ + brow * 64 + bc * 8);                  \
    }                                                                        \
    __builtin_amdgcn_s_setprio(1);                       /* T5 */            \
    _Pragma("unroll")                                                        \
    for (int fn = 0; fn < 6; ++fn)                                           \
      _Pragma("unroll")                                                      \
      for (int fm = 0; fm < 4; ++fm)                                         \
        acc[fn][fm] = MFMA16(bq[fn], af[fm], acc[fn][fm]);   /* W·X^T */     \
    __builtin_amdgcn_s_setprio(0);                                           \
  } } while (0)

#define ITER(T, ACUR, ANXT, WTOP) do {                                       \
  asm volatile("s_waitcnt vmcnt(" #WTOP ")" ::: "memory");                   \
  __builtin_amdgcn_s_barrier();                                              \
  COMPUTE((T) & 1);                                                          \
  asm volatile("s_waitcnt lgkmcnt(0)" ::: "memory");  /* WAR drain */        \
  __builtin_amdgcn_s_barrier();                                              \
  if ((T) + 2 < 6) {                                                         \
    STAGE_B((T) + 2, (T) & 1);                                               \
    asm volatile("s_waitcnt vmcnt(6)" ::: "memory");  /* A(T+2) landed */    \
    AWRITE(ACUR, (T) & 1);                                                   \
    if ((T) + 3 < 6) ALOAD(ANXT, (T) + 3);                                   \
    asm volatile("s_waitcnt lgkmcnt(0)" ::: "memory"); /* writes drained */  \
  } } while (0)

  // prologue: A0,A1 (16 vm) + B0,B1 (12 vm)
  ALOAD(a0, 0);
  ALOAD(a1, 1);
  STAGE_B(0, 0);
  STAGE_B(1, 1);
  asm volatile("s_waitcnt vmcnt(20)" ::: "memory");   // a0 landed
  AWRITE(a0, 0);
  asm volatile("s_waitcnt vmcnt(12)" ::: "memory");   // a1 landed
  AWRITE(a1, 1);
  ALOAD(a0, 2);                                       // A for iter 2, early
  asm volatile("s_waitcnt lgkmcnt(0)" ::: "memory");  // our ds_writes done

  ITER(0, a0, a1, 14);
  ITER(1, a1, a0, 14);
  ITER(2, a0, a1, 14);
  ITER(3, a1, a0, 14);
  ITER(4, a0, a1, 6);
  ITER(5, a1, a0, 0);
#undef ITER
#undef COMPUTE
#undef STAGE_B
#undef AWRITE
#undef ALOAD

  // final ITER's lgkm(0)+barrier drained all GEMM LDS reads block-wide;
  // per-wave attn scratch below may overwrite the staging region.

  // ---- attention, one (window, head) per wave; Q/K stay in registers ----
  const int w = mt * 2 + wm, h = hg * 2 + wn;
  short* Vts = lds + wv * 4992;          // [32][76] V^T (stride 76: no 4-way)
  short* Os  = Vts + 2432;               // [64][40] epilogue staging

  // V scatter: Vts[d][tok], d = fv*16+lg*4+r, tok = fm*16+lr
#pragma unroll
  for (int fv = 0; fv < 2; ++fv)
#pragma unroll
    for (int fm = 0; fm < 4; ++fm)
#pragma unroll
      for (int r = 0; r < 4; ++r)
        Vts[(fv * 16 + lg * 4 + r) * 76 + fm * 16 + lr] =
            f2bf(acc[4 + fv][fm][r]);

  // pack K (A-op: lane=row kt) and Q (B-op: lane=col q) frags in-register;
  // slot j -> d = 16*(j>>2) + 4*lg + (j&3)  (same sigma on both operands)
  s16x8 ka[4], qb[4];
#pragma unroll
  for (int f = 0; f < 4; ++f) {
    s16x8 tk, tq;
#pragma unroll
    for (int j = 0; j < 8; ++j) {
      tk[j] = f2bf(acc[2 + (j >> 2)][f][j & 3]);
      tq[j] = f2bf(acc[0 + (j >> 2)][f][j & 3]);
    }
    ka[f] = tk; qb[f] = tq;
  }

  // S^T = K·Q^T  (rows kt, cols q), K-dim 32
  f32x4 st[4][4];
  __builtin_amdgcn_s_setprio(1);
#pragma unroll
  for (int fk = 0; fk < 4; ++fk)
#pragma unroll
    for (int fq = 0; fq < 4; ++fq)
      st[fk][fq] = MFMA16(ka[fk], qb[fq], (f32x4)0.0f);
  __builtin_amdgcn_s_setprio(0);

  // scale + bias + softmax over kt (per q column, per-lane + shfl 16/32)
  const float* bh = biasF + h * 4096;
#pragma unroll
  for (int fq = 0; fq < 4; ++fq) {
    const int q = fq * 16 + lr;
    float4 bv[4];
#pragma unroll
    for (int fk = 0; fk < 4; ++fk)
      bv[fk] = *(const float4*)(bh + q * 64 + fk * 16 + lg * 4);
    float mx = -3.0e38f;
#pragma unroll
    for (int fk = 0; fk < 4; ++fk)
#pragma unroll
      for (int r = 0; r < 4; ++r) {
        float v = st[fk][fq][r] * 0.17677669529663687f + ((const float*)&bv[fk])[r];
        st[fk][fq][r] = v;
        mx = fmaxf(mx, v);
      }
    mx = fmaxf(mx, __shfl_xor(mx, 16));
    mx = fmaxf(mx, __shfl_xor(mx, 32));
    float sm = 0.0f;
#pragma unroll
    for (int fk = 0; fk < 4; ++fk)
#pragma unroll
      for (int r = 0; r < 4; ++r) {
        float e = __expf(st[fk][fq][r] - mx);
        st[fk][fq][r] = e;
        sm += e;
      }
    sm += __shfl_xor(sm, 16);
    sm += __shfl_xor(sm, 32);
    const float inv = 1.0f / sm;
#pragma unroll
    for (int fk = 0; fk < 4; ++fk)
#pragma unroll
      for (int r = 0; r < 4; ++r) st[fk][fq][r] *= inv;
  }

  // O^T = V^T · P^T ; sigma(g,j)=32kb+16(j>>2)+4g+(j&3) on both operands
  s16x8 va[2][2];
#pragma unroll
  for (int fd = 0; fd < 2; ++fd)
#pragma unroll
    for (int kb = 0; kb < 2; ++kb) {
      short4 v0 = *(const short4*)(Vts + (fd * 16 + lr) * 76 + kb * 32 + lg * 4);
      short4 v1 = *(const short4*)(Vts + (fd * 16 + lr) * 76 + kb * 32 + 16 + lg * 4);
      s16x8 tv;
      tv[0] = v0.x; tv[1] = v0.y; tv[2] = v0.z; tv[3] = v0.w;
      tv[4] = v1.x; tv[5] = v1.y; tv[6] = v1.z; tv[7] = v1.w;
      va[fd][kb] = tv;
    }
  f32x4 ot[2][4];
#pragma unroll
  for (int fd = 0; fd < 2; ++fd)
#pragma unroll
    for (int fq = 0; fq < 4; ++fq) ot[fd][fq] = (f32x4)0.0f;
#pragma unroll
  for (int kb = 0; kb < 2; ++kb)
#pragma unroll
    for (int fq = 0; fq < 4; ++fq) {
      s16x8 pb;
#pragma unroll
      for (int j = 0; j < 8; ++j)
        pb[j] = f2bf(st[2 * kb + (j >> 2)][fq][j & 3]);   // lane-local repack
      __builtin_amdgcn_s_setprio(1);
#pragma unroll
      for (int fd = 0; fd < 2; ++fd)
        ot[fd][fq] = MFMA16(va[fd][kb], pb, ot[fd][fq]);
      __builtin_amdgcn_s_setprio(0);
    }

  // epilogue: stage O [q][d] in Os, write coalesced 64B rows
#pragma unroll
  for (int fd = 0; fd < 2; ++fd)
#pragma unroll
    for (int fq = 0; fq < 4; ++fq)
#pragma unroll
      for (int r = 0; r < 4; ++r)
        Os[(fq * 16 + lr) * 40 + fd * 16 + lg * 4 + r] = f2bf(ot[fd][fq][r]);
  short* dst = AO + ((size_t)w * 64 + l) * 384 + h * 32;
  int4 o0 = *(const int4*)(Os + l * 40);
  int4 o1 = *(const int4*)(Os + l * 40 + 8);
  int4 o2 = *(const int4*)(Os + l * 40 + 16);
  int4 o3 = *(const int4*)(Os + l * 40 + 24);
  *(int4*)(dst)      = o0;
  *(int4*)(dst + 8)  = o1;
  *(int4*)(dst + 16) = o2;
  *(int4*)(dst + 24) = o3;
}

// ---------------- output projection: out = AO(bf16) @ Wo + bo, f32 out --------
// R7-proven BK=64 2-deep counted-vmcnt pipeline (+T5 setprio).
__global__ __launch_bounds__(256) void proj_kernel(
    const short* __restrict__ AO, const short* __restrict__ WoT,
    const float* __restrict__ bo, float* __restrict__ out)
{
  __shared__ short lds[32768];
  const int bid = blockIdx.x;
  const int wg = (bid & 7) * 294 + (bid >> 3);   // XCD swizzle (2352 = 8*294)
  const int nt = wg % 3, mt = wg / 3;
  const int t = threadIdx.x;
  const int wv = t >> 6, l = t & 63, lr = l & 15, lg = l >> 4;
  const int wm = wv >> 1, wn = wv & 1;

  f32x4 acc[4][4];
#pragma unroll
  for (int fm = 0; fm < 4; ++fm)
#pragma unroll
    for (int fn = 0; fn < 4; ++fn) acc[fm][fn] = (f32x4)0.0f;

  const int srow = wv * 32 + (l >> 3);
  const int cg = (l & 7) ^ (srow & 7);
  const short* Ab = AO  + (size_t)(mt * 128 + srow) * 384 + cg * 8;
  const short* Bb = WoT + (size_t)(nt * 128 + srow) * 384 + cg * 8;

#define STAGE(KS, SEL) do {                                                  \
  _Pragma("unroll")                                                          \
  for (int i_ = 0; i_ < 4; ++i_) {                                           \
    gload_lds16(Ab + i_ * 3072 + (KS) * 64,                                  \
                lds + (SEL) * 16384 + (wv * 4 + i_) * 512);                  \
    gload_lds16(Bb + i_ * 3072 + (KS) * 64,                                  \
                lds + (SEL) * 16384 + 8192 + (wv * 4 + i_) * 512);           \
  } } while (0)

#define COMPUTE(SEL) do {                                                    \
  const short* Acur_ = lds + (SEL) * 16384;                                  \
  const short* Bcur_ = Acur_ + 8192;                                         \
  _Pragma("unroll")                                                          \
  for (int kk = 0; kk < 2; ++kk) {                                           \
    s16x8 af[4], bf[4];                                                      \
    _Pragma("unroll")                                                        \
    for (int f = 0; f < 4; ++f) {                                            \
      const int arow = wm * 64 + f * 16 + lr;                                \
      const int ac = (kk * 4 + lg) ^ (arow & 7);                             \
      af[f] = *(const s16x8*)(Acur_ + arow * 64 + ac * 8);                   \
      const int brow = wn * 64 + f * 16 + lr;                                \
      const int bc = (kk * 4 + lg) ^ (brow & 7);                             \
      bf[f] = *(const s16x8*)(Bcur_ + brow * 64 + bc * 8);                   \
    }                                                                        \
    __builtin_amdgcn_s_setprio(1);                       /* T5 */            \
    _Pragma("unroll")                                                        \
    for (int fm = 0; fm < 4; ++fm)                                           \
      _Pragma("unroll")                                                      \
      for (int fn = 0; fn < 4; ++fn)                                         \
        acc[fm][fn] = MFMA16(af[fm], bf[fn], acc[fm][fn]);                   \
    __builtin_amdgcn_s_setprio(0);                                           \
  } } while (0)

#define ITER(T, WN) do {                                                     \
  asm volatile("s_waitcnt vmcnt(" #WN ")" ::: "memory");                     \
  __builtin_amdgcn_s_barrier();                                              \
  COMPUTE((T) & 1);                                                          \
  asm volatile("s_waitcnt lgkmcnt(0)" ::: "memory");  /* WAR drain */        \
  __builtin_amdgcn_s_barrier();                                              \
  if ((T) + 2 < 6) STAGE((T) + 2, (T) & 1);                                  \
  } while (0)

  STAGE(0, 0);
  STAGE(1, 1);
  ITER(0, 8); ITER(1, 8); ITER(2, 8); ITER(3, 8); ITER(4, 8); ITER(5, 0);
#undef ITER
#undef COMPUTE
#undef STAGE

#pragma unroll
  for (int fn = 0; fn < 4; ++fn) {
    const int n = nt * 128 + wn * 64 + fn * 16 + lr;
    const float bias = bo[n];
#pragma unroll
    for (int fm = 0; fm < 4; ++fm) {
      const int m0 = mt * 128 + wm * 64 + fm * 16 + lg * 4;
#pragma unroll
      for (int r = 0; r < 4; ++r)
        out[(size_t)(m0 + r) * 384 + n] = acc[fm][fn][r] + bias;
    }
  }
}

extern "C" void kernel_launch(void* const* d_in, const int* in_sizes, int n_in,
                              void* d_out, int out_size, void* d_ws, size_t ws_size,
                              hipStream_t stream)
{
  const float* X    = (const float*)d_in[0];
  const float* Wqkv = (const float*)d_in[1];
  const float* posb = (const float*)d_in[2];
  const float* Wo   = (const float*)d_in[3];
  const float* bo   = (const float*)d_in[4];
  const int*   relp = (const int*)d_in[5];
  float* out = (float*)d_out;

  // workspace carve — ~78.5 MB (Xbf eliminated)
  char* ws = (char*)d_ws;
  short* WqkvT = (short*)(ws);                 //   884,736 B
  short* WoT   = (short*)(ws + 884736);        //   294,912 B
  float* biasF = (float*)(ws + 1179648);       //   196,608 B
  short* AO    = (short*)(ws + 1376256);       // 77,070,336 B [100352][384]

  prep_kernel<<<2496, 256, 0, stream>>>(Wqkv, Wo, posb, relp, WqkvT, WoT, biasF);
  qkv_attn<<<4704, 256, 0, stream>>>(X, WqkvT, biasF, AO);
  proj_kernel<<<2352, 256, 0, stream>>>(AO, WoT, bo, out);
}

// Round 23
// 220.545 us; speedup vs baseline: 1.3191x; 1.0060x over previous
//
#include <hip/hip_runtime.h>
#include <hip/hip_bf16.h>

typedef float f32x4 __attribute__((ext_vector_type(4)));
typedef short s16x8 __attribute__((ext_vector_type(8)));

#define MFMA16(A,B,C) __builtin_amdgcn_mfma_f32_16x16x32_bf16((A),(B),(C),0,0,0)

// Hardware RNE f32->bf16 (v_cvt_pk_bf16_f32 when paired).
__device__ __forceinline__ short f2bf(float f) {
  return (short)__bfloat16_as_ushort(__float2bfloat16(f));
}

__device__ __forceinline__ void gload_lds16(const void* g, void* l) {
  __builtin_amdgcn_global_load_lds(
      (const __attribute__((address_space(1))) unsigned*)g,
      (__attribute__((address_space(3))) unsigned*)l, 16, 0, 0);
}

// ---------------- prep: weights -> bf16[N][K], gather bias table --------------
__global__ __launch_bounds__(256) void prep_kernel(
    const float* __restrict__ Wqkv, const float* __restrict__ Wo,
    const float* __restrict__ posb, const int* __restrict__ relp,
    short* __restrict__ WqkvT, short* __restrict__ WoT, float* __restrict__ biasF)
{
  int i = blockIdx.x * 256 + threadIdx.x;     // 2496*256 = 638,976 exactly
  if (i < 1152 * 384) {
    int n = i / 384, k = i % 384;
    WqkvT[i] = f2bf(Wqkv[k * 1152 + n]);
  } else if (i < 1152 * 384 + 384 * 384) {
    int j = i - 1152 * 384;
    int n = j / 384, k = j % 384;
    WoT[j] = f2bf(Wo[k * 384 + n]);
  } else {
    int j = i - (1152 * 384 + 384 * 384);     // j < 12*64*64 = 49152
    int h = j >> 12, qk = j & 4095;
    biasF[j] = posb[h * 16129 + relp[qk]];
  }
}

// ---------------- fused X-convert + QKV GEMM + attention (2 heads / block) ----
// FINAL (R19 configuration, measured best 221.2us total; qkv_attn 194us):
// - swapped-operand GEMM acc' = W·X^T, 128 tok x 192 col tile, BK=64
// - A: f32 X loaded to regs (2 sets), cvt, ds_write_b128 (fused conversion —
//   deletes the standalone 231MB xcvt pass)
// - B: global_load_lds into LDS dbuf, both-sides XOR chunk involution
// - 2-deep counted-vmcnt pipeline, lgkm WAR drain before 2nd barrier
//   (R7-proven ordering; R4/R6 raced without the drain)
// - attention per (window,head) wave: Q/K packed lane-locally from acc
//   (sigma''(lg,j)=16(j>>2)+4lg+(j&3) on both operands), V via LDS transpose
//   stride 76, in-register softmax (shfl 16/32), sigma-repacked PV
// Refuted variants: BK=32 (R9 conflicts), B-from-global (R16 spill/R17
// latency), 3rd reg set (R20 VGPR 140 -> occ 11%), top-ALOAD (R21 null),
// setprio (R22 null). Remaining headroom requires the 8-phase restructure.
__global__ __launch_bounds__(256) void qkv_attn(
    const float* __restrict__ X, const short* __restrict__ WqkvT,
    const float* __restrict__ biasF, short* __restrict__ AO)
{
  __shared__ short lds[40960];   // A: sel*8192 | B: 16384 + sel*12288 (shorts)
  const int bid = blockIdx.x;
  const int wg = (bid & 7) * 588 + (bid >> 3);   // XCD swizzle (4704 = 8*588)
  const int hg = wg % 6, mt = wg / 6;
  const int t = threadIdx.x;
  const int wv = t >> 6, l = t & 63, lr = l & 15, lg = l >> 4;
  const int wm = wv >> 1, wn = wv & 1;

  f32x4 acc[6][4];               // [fn: q0,q1,k0,k1,v0,v1][fm: token block]
#pragma unroll
  for (int fn = 0; fn < 6; ++fn)
#pragma unroll
    for (int fm = 0; fm < 4; ++fm) acc[fn][fm] = (f32x4)0.0f;

  const int cgs = (l & 7) ^ (l >> 3);
  const float* Axf = X + (size_t)(mt * 128 + wv * 32 + (l >> 3)) * 384 + cgs * 8;
  const int adst = (wv * 32 + (l >> 3)) * 64 + (l & 7) * 8;  // + i*512, shorts
  const short* BbT[6];
#pragma unroll
  for (int j = 0; j < 6; ++j) {
    const int n0 = wv * 48 + j * 8 + (l >> 3);
    const int hl = n0 / 96, rem = n0 % 96;
    const int p = rem >> 5, d = rem & 31;
    BbT[j] = WqkvT + (size_t)(p * 384 + hg * 64 + hl * 32 + d) * 384 + cgs * 8;
  }

  float4 a0[8], a1[8];

#define ALOAD(SET, KS) do {                                                  \
  _Pragma("unroll")                                                          \
  for (int i_ = 0; i_ < 4; ++i_) {                                           \
    const float* p_ = Axf + i_ * 8 * 384 + (KS) * 64;                        \
    SET[2 * i_]     = *(const float4*)p_;                                    \
    SET[2 * i_ + 1] = *(const float4*)(p_ + 4);                              \
  } } while (0)

#define AWRITE(SET, SEL) do {                                                \
  _Pragma("unroll")                                                          \
  for (int i_ = 0; i_ < 4; ++i_) {                                           \
    s16x8 pk_;                                                               \
    pk_[0] = f2bf(SET[2*i_].x);   pk_[1] = f2bf(SET[2*i_].y);                \
    pk_[2] = f2bf(SET[2*i_].z);   pk_[3] = f2bf(SET[2*i_].w);                \
    pk_[4] = f2bf(SET[2*i_+1].x); pk_[5] = f2bf(SET[2*i_+1].y);              \
    pk_[6] = f2bf(SET[2*i_+1].z); pk_[7] = f2bf(SET[2*i_+1].w);              \
    *(s16x8*)(lds + (SEL) * 8192 + adst + i_ * 512) = pk_;                   \
  } } while (0)

#define STAGE_B(KS, SEL) do {                                                \
  _Pragma("unroll")                                                          \
  for (int j_ = 0; j_ < 6; ++j_)                                             \
    gload_lds16(BbT[j_] + (KS) * 64,                                         \
                lds + 16384 + (SEL) * 12288 + (wv * 6 + j_) * 512);          \
  } while (0)

#define COMPUTE(SEL) do {                                                    \
  const short* Acur_ = lds + (SEL) * 8192;                                   \
  const short* Bcur_ = lds + 16384 + (SEL) * 12288;                          \
  _Pragma("unroll")                                                          \
  for (int kk = 0; kk < 2; ++kk) {                                           \
    s16x8 af[4], bq[6];                                                      \
    _Pragma("unroll")                                                        \
    for (int f = 0; f < 4; ++f) {                                            \
      const int arow = wm * 64 + f * 16 + lr;                                \
      const int ac = (kk * 4 + lg) ^ (arow & 7);                             \
      af[f] = *(const s16x8*)(Acur_ + arow * 64 + ac * 8);                   \
    }                                                                        \
    _Pragma("unroll")                                                        \
    for (int fn = 0; fn < 6; ++fn) {                                         \
      const int brow = wn * 96 + fn * 16 + lr;                               \
      const int bc = (kk * 4 + lg) ^ (brow & 7);                             \
      bq[fn] = *(const s16x8*)(Bcur_ + brow * 64 + bc * 8);                  \
    }                                                                        \
    _Pragma("unroll")                                                        \
    for (int fn = 0; fn < 6; ++fn)                                           \
      _Pragma("unroll")                                                      \
      for (int fm = 0; fm < 4; ++fm)                                         \
        acc[fn][fm] = MFMA16(bq[fn], af[fm], acc[fn][fm]);   /* W·X^T */     \
  } } while (0)

#define ITER(T, ACUR, ANXT, WTOP) do {                                       \
  asm volatile("s_waitcnt vmcnt(" #WTOP ")" ::: "memory");                   \
  __builtin_amdgcn_s_barrier();                                              \
  COMPUTE((T) & 1);                                                          \
  asm volatile("s_waitcnt lgkmcnt(0)" ::: "memory");  /* WAR drain */        \
  __builtin_amdgcn_s_barrier();                                              \
  if ((T) + 2 < 6) {                                                         \
    STAGE_B((T) + 2, (T) & 1);                                               \
    asm volatile("s_waitcnt vmcnt(6)" ::: "memory");  /* A(T+2) landed */    \
    AWRITE(ACUR, (T) & 1);                                                   \
    if ((T) + 3 < 6) ALOAD(ANXT, (T) + 3);                                   \
    asm volatile("s_waitcnt lgkmcnt(0)" ::: "memory"); /* writes drained */  \
  } } while (0)

  // prologue: A0,A1 (16 vm) + B0,B1 (12 vm)
  ALOAD(a0, 0);
  ALOAD(a1, 1);
  STAGE_B(0, 0);
  STAGE_B(1, 1);
  asm volatile("s_waitcnt vmcnt(20)" ::: "memory");   // a0 landed
  AWRITE(a0, 0);
  asm volatile("s_waitcnt vmcnt(12)" ::: "memory");   // a1 landed
  AWRITE(a1, 1);
  ALOAD(a0, 2);                                       // A for iter 2, early
  asm volatile("s_waitcnt lgkmcnt(0)" ::: "memory");  // our ds_writes done

  ITER(0, a0, a1, 14);
  ITER(1, a1, a0, 14);
  ITER(2, a0, a1, 14);
  ITER(3, a1, a0, 14);
  ITER(4, a0, a1, 6);
  ITER(5, a1, a0, 0);
#undef ITER
#undef COMPUTE
#undef STAGE_B
#undef AWRITE
#undef ALOAD

  // final ITER's lgkm(0)+barrier drained all GEMM LDS reads block-wide;
  // per-wave attn scratch below may overwrite the staging region.

  // ---- attention, one (window, head) per wave; Q/K stay in registers ----
  const int w = mt * 2 + wm, h = hg * 2 + wn;
  short* Vts = lds + wv * 4992;          // [32][76] V^T (stride 76: no 4-way)
  short* Os  = Vts + 2432;               // [64][40] epilogue staging

  // V scatter: Vts[d][tok], d = fv*16+lg*4+r, tok = fm*16+lr
#pragma unroll
  for (int fv = 0; fv < 2; ++fv)
#pragma unroll
    for (int fm = 0; fm < 4; ++fm)
#pragma unroll
      for (int r = 0; r < 4; ++r)
        Vts[(fv * 16 + lg * 4 + r) * 76 + fm * 16 + lr] =
            f2bf(acc[4 + fv][fm][r]);

  // pack K (A-op: lane=row kt) and Q (B-op: lane=col q) frags in-register;
  // slot j -> d = 16*(j>>2) + 4*lg + (j&3)  (same sigma on both operands)
  s16x8 ka[4], qb[4];
#pragma unroll
  for (int f = 0; f < 4; ++f) {
    s16x8 tk, tq;
#pragma unroll
    for (int j = 0; j < 8; ++j) {
      tk[j] = f2bf(acc[2 + (j >> 2)][f][j & 3]);
      tq[j] = f2bf(acc[0 + (j >> 2)][f][j & 3]);
    }
    ka[f] = tk; qb[f] = tq;
  }

  // S^T = K·Q^T  (rows kt, cols q), K-dim 32
  f32x4 st[4][4];
#pragma unroll
  for (int fk = 0; fk < 4; ++fk)
#pragma unroll
    for (int fq = 0; fq < 4; ++fq)
      st[fk][fq] = MFMA16(ka[fk], qb[fq], (f32x4)0.0f);

  // scale + bias + softmax over kt (per q column, per-lane + shfl 16/32)
  const float* bh = biasF + h * 4096;
#pragma unroll
  for (int fq = 0; fq < 4; ++fq) {
    const int q = fq * 16 + lr;
    float4 bv[4];
#pragma unroll
    for (int fk = 0; fk < 4; ++fk)
      bv[fk] = *(const float4*)(bh + q * 64 + fk * 16 + lg * 4);
    float mx = -3.0e38f;
#pragma unroll
    for (int fk = 0; fk < 4; ++fk)
#pragma unroll
      for (int r = 0; r < 4; ++r) {
        float v = st[fk][fq][r] * 0.17677669529663687f + ((const float*)&bv[fk])[r];
        st[fk][fq][r] = v;
        mx = fmaxf(mx, v);
      }
    mx = fmaxf(mx, __shfl_xor(mx, 16));
    mx = fmaxf(mx, __shfl_xor(mx, 32));
    float sm = 0.0f;
#pragma unroll
    for (int fk = 0; fk < 4; ++fk)
#pragma unroll
      for (int r = 0; r < 4; ++r) {
        float e = __expf(st[fk][fq][r] - mx);
        st[fk][fq][r] = e;
        sm += e;
      }
    sm += __shfl_xor(sm, 16);
    sm += __shfl_xor(sm, 32);
    const float inv = 1.0f / sm;
#pragma unroll
    for (int fk = 0; fk < 4; ++fk)
#pragma unroll
      for (int r = 0; r < 4; ++r) st[fk][fq][r] *= inv;
  }

  // O^T = V^T · P^T ; sigma(g,j)=32kb+16(j>>2)+4g+(j&3) on both operands
  s16x8 va[2][2];
#pragma unroll
  for (int fd = 0; fd < 2; ++fd)
#pragma unroll
    for (int kb = 0; kb < 2; ++kb) {
      short4 v0 = *(const short4*)(Vts + (fd * 16 + lr) * 76 + kb * 32 + lg * 4);
      short4 v1 = *(const short4*)(Vts + (fd * 16 + lr) * 76 + kb * 32 + 16 + lg * 4);
      s16x8 tv;
      tv[0] = v0.x; tv[1] = v0.y; tv[2] = v0.z; tv[3] = v0.w;
      tv[4] = v1.x; tv[5] = v1.y; tv[6] = v1.z; tv[7] = v1.w;
      va[fd][kb] = tv;
    }
  f32x4 ot[2][4];
#pragma unroll
  for (int fd = 0; fd < 2; ++fd)
#pragma unroll
    for (int fq = 0; fq < 4; ++fq) ot[fd][fq] = (f32x4)0.0f;
#pragma unroll
  for (int kb = 0; kb < 2; ++kb)
#pragma unroll
    for (int fq = 0; fq < 4; ++fq) {
      s16x8 pb;
#pragma unroll
      for (int j = 0; j < 8; ++j)
        pb[j] = f2bf(st[2 * kb + (j >> 2)][fq][j & 3]);   // lane-local repack
#pragma unroll
      for (int fd = 0; fd < 2; ++fd)
        ot[fd][fq] = MFMA16(va[fd][kb], pb, ot[fd][fq]);
    }

  // epilogue: stage O [q][d] in Os, write coalesced 64B rows
#pragma unroll
  for (int fd = 0; fd < 2; ++fd)
#pragma unroll
    for (int fq = 0; fq < 4; ++fq)
#pragma unroll
      for (int r = 0; r < 4; ++r)
        Os[(fq * 16 + lr) * 40 + fd * 16 + lg * 4 + r] = f2bf(ot[fd][fq][r]);
  short* dst = AO + ((size_t)w * 64 + l) * 384 + h * 32;
  int4 o0 = *(const int4*)(Os + l * 40);
  int4 o1 = *(const int4*)(Os + l * 40 + 8);
  int4 o2 = *(const int4*)(Os + l * 40 + 16);
  int4 o3 = *(const int4*)(Os + l * 40 + 24);
  *(int4*)(dst)      = o0;
  *(int4*)(dst + 8)  = o1;
  *(int4*)(dst + 16) = o2;
  *(int4*)(dst + 24) = o3;
}

// ---------------- output projection: out = AO(bf16) @ Wo + bo, f32 out --------
// R7-proven BK=64 2-deep counted-vmcnt pipeline.
__global__ __launch_bounds__(256) void proj_kernel(
    const short* __restrict__ AO, const short* __restrict__ WoT,
    const float* __restrict__ bo, float* __restrict__ out)
{
  __shared__ short lds[32768];
  const int bid = blockIdx.x;
  const int wg = (bid & 7) * 294 + (bid >> 3);   // XCD swizzle (2352 = 8*294)
  const int nt = wg % 3, mt = wg / 3;
  const int t = threadIdx.x;
  const int wv = t >> 6, l = t & 63, lr = l & 15, lg = l >> 4;
  const int wm = wv >> 1, wn = wv & 1;

  f32x4 acc[4][4];
#pragma unroll
  for (int fm = 0; fm < 4; ++fm)
#pragma unroll
    for (int fn = 0; fn < 4; ++fn) acc[fm][fn] = (f32x4)0.0f;

  const int srow = wv * 32 + (l >> 3);
  const int cg = (l & 7) ^ (srow & 7);
  const short* Ab = AO  + (size_t)(mt * 128 + srow) * 384 + cg * 8;
  const short* Bb = WoT + (size_t)(nt * 128 + srow) * 384 + cg * 8;

#define STAGE(KS, SEL) do {                                                  \
  _Pragma("unroll")                                                          \
  for (int i_ = 0; i_ < 4; ++i_) {                                           \
    gload_lds16(Ab + i_ * 3072 + (KS) * 64,                                  \
                lds + (SEL) * 16384 + (wv * 4 + i_) * 512);                  \
    gload_lds16(Bb + i_ * 3072 + (KS) * 64,                                  \
                lds + (SEL) * 16384 + 8192 + (wv * 4 + i_) * 512);           \
  } } while (0)

#define COMPUTE(SEL) do {                                                    \
  const short* Acur_ = lds + (SEL) * 16384;                                  \
  const short* Bcur_ = Acur_ + 8192;                                         \
  _Pragma("unroll")                                                          \
  for (int kk = 0; kk < 2; ++kk) {                                           \
    s16x8 af[4], bf[4];                                                      \
    _Pragma("unroll")                                                        \
    for (int f = 0; f < 4; ++f) {                                            \
      const int arow = wm * 64 + f * 16 + lr;                                \
      const int ac = (kk * 4 + lg) ^ (arow & 7);                             \
      af[f] = *(const s16x8*)(Acur_ + arow * 64 + ac * 8);                   \
      const int brow = wn * 64 + f * 16 + lr;                                \
      const int bc = (kk * 4 + lg) ^ (brow & 7);                             \
      bf[f] = *(const s16x8*)(Bcur_ + brow * 64 + bc * 8);                   \
    }                                                                        \
    _Pragma("unroll")                                                        \
    for (int fm = 0; fm < 4; ++fm)                                           \
      _Pragma("unroll")                                                      \
      for (int fn = 0; fn < 4; ++fn)                                         \
        acc[fm][fn] = MFMA16(af[fm], bf[fn], acc[fm][fn]);                   \
  } } while (0)

#define ITER(T, WN) do {                                                     \
  asm volatile("s_waitcnt vmcnt(" #WN ")" ::: "memory");                     \
  __builtin_amdgcn_s_barrier();                                              \
  COMPUTE((T) & 1);                                                          \
  asm volatile("s_waitcnt lgkmcnt(0)" ::: "memory");  /* WAR drain */        \
  __builtin_amdgcn_s_barrier();                                              \
  if ((T) + 2 < 6) STAGE((T) + 2, (T) & 1);                                  \
  } while (0)

  STAGE(0, 0);
  STAGE(1, 1);
  ITER(0, 8); ITER(1, 8); ITER(2, 8); ITER(3, 8); ITER(4, 8); ITER(5, 0);
#undef ITER
#undef COMPUTE
#undef STAGE

#pragma unroll
  for (int fn = 0; fn < 4; ++fn) {
    const int n = nt * 128 + wn * 64 + fn * 16 + lr;
    const float bias = bo[n];
#pragma unroll
    for (int fm = 0; fm < 4; ++fm) {
      const int m0 = mt * 128 + wm * 64 + fm * 16 + lg * 4;
#pragma unroll
      for (int r = 0; r < 4; ++r)
        out[(size_t)(m0 + r) * 384 + n] = acc[fm][fn][r] + bias;
    }
  }
}

extern "C" void kernel_launch(void* const* d_in, const int* in_sizes, int n_in,
                              void* d_out, int out_size, void* d_ws, size_t ws_size,
                              hipStream_t stream)
{
  const float* X    = (const float*)d_in[0];
  const float* Wqkv = (const float*)d_in[1];
  const float* posb = (const float*)d_in[2];
  const float* Wo   = (const float*)d_in[3];
  const float* bo   = (const float*)d_in[4];
  const int*   relp = (const int*)d_in[5];
  float* out = (float*)d_out;

  // workspace carve — ~78.5 MB
  char* ws = (char*)d_ws;
  short* WqkvT = (short*)(ws);                 //   884,736 B
  short* WoT   = (short*)(ws + 884736);        //   294,912 B
  float* biasF = (float*)(ws + 1179648);       //   196,608 B
  short* AO    = (short*)(ws + 1376256);       // 77,070,336 B [100352][384]

  prep_kernel<<<2496, 256, 0, stream>>>(Wqkv, Wo, posb, relp, WqkvT, WoT, biasF);
  qkv_attn<<<4704, 256, 0, stream>>>(X, WqkvT, biasF, AO);
  proj_kernel<<<2352, 256, 0, stream>>>(AO, WoT, bo, out);
}